// Round 4
// baseline (659.683 us; speedup 1.0000x reference)
//
#include <hip/hip_runtime.h>

typedef unsigned short u16;
typedef __attribute__((ext_vector_type(8))) short bf16x8;
typedef __attribute__((ext_vector_type(4))) float f32x4;

#define MFMA16(a, b, c) __builtin_amdgcn_mfma_f32_16x16x32_bf16((a), (b), (c), 0, 0, 0)

// d_ws layout (u16 element offsets)
#define OFF_WQ   0
#define OFF_WG   65536
#define OFF_WC1  131072
#define OFF_WO   163840
#define OFF_KNF  229376   // normalized fast keys  [h][s][d]
#define OFF_VTF  245760   // fast vals transposed  [h][d][s]
#define OFF_KND  262144
#define OFF_VTD  278528

__device__ __forceinline__ u16 f2b(float f) {
  union { float f; unsigned u; } v; v.f = f;
  unsigned r = v.u + 0x7fffu + ((v.u >> 16) & 1u);  // RNE fp32->bf16
  return (u16)(r >> 16);
}
__device__ __forceinline__ float fsig(float x) {
  return __builtin_amdgcn_rcpf(1.f + __expf(-x));
}
__device__ __forceinline__ float ftanh(float x) {
  float e = __expf(2.f * x);
  return (e - 1.f) * __builtin_amdgcn_rcpf(e + 1.f);
}
__device__ __forceinline__ float sum16(float v) {  // reduce across l16 lanes (within quad)
  v += __shfl_xor(v, 1);
  v += __shfl_xor(v, 2);
  v += __shfl_xor(v, 4);
  v += __shfl_xor(v, 8);
  return v;
}
__device__ __forceinline__ float sum64(float v) {
  v = sum16(v);
  v += __shfl_xor(v, 16);
  v += __shfl_xor(v, 32);
  return v;
}

// ---------- pre-kernel: weights fp32 -> bf16 ----------
__global__ void k_convert(const float* __restrict__ Wq, const float* __restrict__ Wg,
                          const float* __restrict__ Wc1, const float* __restrict__ Wo,
                          u16* __restrict__ ws) {
  int i = blockIdx.x * 256 + threadIdx.x;  // 65536 threads
  ws[OFF_WQ + i] = f2b(Wq[i]);
  ws[OFF_WG + i] = f2b(Wg[i]);
  ws[OFF_WO + i] = f2b(Wo[i]);
  if (i < 32768) ws[OFF_WC1 + i] = f2b(Wc1[i]);
}

// ---------- pre-kernel: normalize keys, transpose vals ----------
__global__ void k_prep(const float* __restrict__ fk, const float* __restrict__ fv,
                       const float* __restrict__ dk, const float* __restrict__ dv,
                       u16* __restrict__ ws) {
  int t = blockIdx.x;        // 0..255 == h*64+s
  int h = t >> 6, s = t & 63;
  int d = threadIdx.x;       // 0..63

  float x = fk[t * 64 + d];
  float ss = sum64(x * x);
  float sc = __builtin_amdgcn_rcpf(__builtin_amdgcn_sqrtf(ss) + 1e-8f);
  ws[OFF_KNF + t * 64 + d] = f2b(x * sc);

  x = dk[t * 64 + d];
  ss = sum64(x * x);
  sc = __builtin_amdgcn_rcpf(__builtin_amdgcn_sqrtf(ss) + 1e-8f);
  ws[OFF_KND + t * 64 + d] = f2b(x * sc);

  ws[OFF_VTF + h * 4096 + d * 64 + s] = f2b(fv[t * 64 + d]);
  ws[OFF_VTD + h * 4096 + d * 64 + s] = f2b(dv[t * 64 + d]);
}

// ---------- single fused kernel, ZERO barriers ----------
// 1024 blocks x 256 threads; each WAVE owns 16 rows and does the entire
// pipeline for them. All reductions (gate mean, conf, q-norm, softmax) are
// within the 16-lane l16 group; all layout transforms (C->A) go through
// wave-PRIVATE LDS. No __syncthreads anywhere -> no vmcnt(0) convoy; 12
// independent waves/CU hide L2/HBM latency.
__global__ __launch_bounds__(256, 3)
void k_main(const float* __restrict__ query, const float* __restrict__ context,
            const float* __restrict__ bq, const float* __restrict__ bg,
            const float* __restrict__ bc1, const float* __restrict__ Wc2,
            const float* __restrict__ bc2v, const float* __restrict__ bo,
            const float* __restrict__ mixl, const u16* __restrict__ ws,
            float* __restrict__ outp) {
  __shared__ u16 sQ[4][16 * 256];  // 8 KB/wave: qn, later out_pre (swizzled)
  __shared__ u16 sP[4][16 * 64];   // 2 KB/wave: attention P matrix (swizzled)

  const int t = threadIdx.x;
  const int w = t >> 6;
  const int lane = t & 63;
  const int quad = lane >> 4;
  const int l16 = lane & 15;
  const int row0 = (blockIdx.x * 4 + w) * 16;  // this wave's 16 global rows
  char* Q = (char*)sQ[w];
  char* P = (char*)sP[w];

  const f32x4 vzero = {0.f, 0.f, 0.f, 0.f};

  // Load 16x256 fp32 activation tile directly into MFMA A-fragments
  // (lane l16 = row, quad*8 = k-slice), converting to bf16 in registers.
  auto load_frags = [&](const float* __restrict__ src, bf16x8* fr) {
    const float* p = src + (size_t)(row0 + l16) * 256 + quad * 8;
    #pragma unroll
    for (int kk = 0; kk < 8; ++kk) {
      float4 v0 = *(const float4*)(p + kk * 32);
      float4 v1 = *(const float4*)(p + kk * 32 + 4);
      bf16x8 a;
      a[0] = (short)f2b(v0.x); a[1] = (short)f2b(v0.y);
      a[2] = (short)f2b(v0.z); a[3] = (short)f2b(v0.w);
      a[4] = (short)f2b(v1.x); a[5] = (short)f2b(v1.y);
      a[6] = (short)f2b(v1.z); a[7] = (short)f2b(v1.w);
      fr[kk] = a;
    }
  };

  bf16x8 fr[8];
  float abx[4], aby[4];  // per-row conf*mix, conf*(1-mix) (rows quad*4+r)

  // ===== context path: gate + conf (wave-local) =====
  load_frags(context, fr);
  {
    f32x4 acc[16];
    #pragma unroll
    for (int nt = 0; nt < 16; ++nt) acc[nt] = vzero;
    const u16* WB = ws + OFF_WG + l16 * 256;
    #pragma unroll
    for (int nt = 0; nt < 16; ++nt)
      #pragma unroll
      for (int kk = 0; kk < 8; ++kk) {
        bf16x8 b = *(const bf16x8*)(WB + nt * 4096 + kk * 32 + quad * 8);
        acc[nt] = MFMA16(fr[kk], b, acc[nt]);
      }
    float gate_r[4];
    #pragma unroll
    for (int r = 0; r < 4; ++r) {
      float s = 0.f;
      #pragma unroll
      for (int nt = 0; nt < 16; ++nt) s += ftanh(acc[nt][r] + bg[nt * 16 + l16]);
      gate_r[r] = sum16(s) * (1.f / 256.f);
    }
    // conf: tanh(ctx @ Wc1^T + bc1) . Wc2
    f32x4 cacc[8];
    #pragma unroll
    for (int nt = 0; nt < 8; ++nt) cacc[nt] = vzero;
    const u16* WC = ws + OFF_WC1 + l16 * 256;
    #pragma unroll
    for (int nt = 0; nt < 8; ++nt)
      #pragma unroll
      for (int kk = 0; kk < 8; ++kk) {
        bf16x8 b = *(const bf16x8*)(WC + nt * 4096 + kk * 32 + quad * 8);
        cacc[nt] = MFMA16(fr[kk], b, cacc[nt]);
      }
    float ml = mixl[0], b2 = bc2v[0];
    #pragma unroll
    for (int r = 0; r < 4; ++r) {
      float s = 0.f;
      #pragma unroll
      for (int nt = 0; nt < 8; ++nt)
        s += ftanh(cacc[nt][r] + bc1[nt * 16 + l16]) * Wc2[nt * 16 + l16];
      float conf = fsig(sum16(s) + b2);
      float mix = fsig(ml + gate_r[r]);
      abx[r] = conf * mix;
      aby[r] = conf - conf * mix;
    }
  }

  // ===== query projection + per-head normalize -> qn in wave-private LDS =====
  load_frags(query, fr);
  {
    f32x4 q[16];
    #pragma unroll
    for (int nt = 0; nt < 16; ++nt) q[nt] = vzero;
    const u16* WB = ws + OFF_WQ + l16 * 256;
    #pragma unroll
    for (int nt = 0; nt < 16; ++nt)
      #pragma unroll
      for (int kk = 0; kk < 8; ++kk) {
        bf16x8 b = *(const bf16x8*)(WB + nt * 4096 + kk * 32 + quad * 8);
        q[nt] = MFMA16(fr[kk], b, q[nt]);
      }
    #pragma unroll
    for (int nt = 0; nt < 16; ++nt) {
      float bv = bq[nt * 16 + l16];
      #pragma unroll
      for (int r = 0; r < 4; ++r) q[nt][r] += bv;
    }
    // per-head L2 norm (head h = nt/4 group), then write qn (bf16, swizzled)
    #pragma unroll
    for (int h = 0; h < 4; ++h) {
      float sc[4];
      #pragma unroll
      for (int r = 0; r < 4; ++r) {
        float ss = 0.f;
        #pragma unroll
        for (int j = 0; j < 4; ++j) { float x = q[h * 4 + j][r]; ss += x * x; }
        ss = sum16(ss);
        sc[r] = __builtin_amdgcn_rcpf(__builtin_amdgcn_sqrtf(ss) + 1e-8f);
      }
      #pragma unroll
      for (int j = 0; j < 4; ++j) {
        int nt = h * 4 + j;
        int col = nt * 16 + l16;
        #pragma unroll
        for (int r = 0; r < 4; ++r) {
          int row = quad * 4 + r;
          *(u16*)(Q + row * 512 + (((((col >> 3) ^ (row & 7)) << 3) | (col & 7)) << 1)) =
              f2b(q[nt][r] * sc[r]);
        }
      }
    }
  }
  __builtin_amdgcn_wave_barrier();  // keep ds_write(qn) before ds_read (in-order DS, sched fence)

  // ===== dual-tier attention, head-sequential, all wave-local =====
  f32x4 o16[16];  // out_pre in C-layout (col = nt*16+l16)
  #pragma unroll
  for (int h = 0; h < 4; ++h) {
    // qn A-frags for this head from LDS
    bf16x8 qf[2];
    #pragma unroll
    for (int kk = 0; kk < 2; ++kk) {
      int col = h * 64 + kk * 32 + quad * 8;
      qf[kk] = *(const bf16x8*)(Q + l16 * 512 + ((((col >> 3) ^ (l16 & 7)) << 4)));
    }
    #pragma unroll
    for (int tier = 0; tier < 2; ++tier) {
      const u16* kn = ws + (tier ? OFF_KND : OFF_KNF) + h * 4096;
      const u16* vt = ws + (tier ? OFF_VTD : OFF_VTF) + h * 4096;
      f32x4 sim[4];
      #pragma unroll
      for (int nt = 0; nt < 4; ++nt) {
        sim[nt] = vzero;
        #pragma unroll
        for (int kk = 0; kk < 2; ++kk) {
          bf16x8 b = *(const bf16x8*)(kn + (nt * 16 + l16) * 64 + kk * 32 + quad * 8);
          sim[nt] = MFMA16(qf[kk], b, sim[nt]);
        }
      }
      // softmax over 64 keys (cosine sims bounded by 1: no max-subtract)
      #pragma unroll
      for (int r = 0; r < 4; ++r) {
        float rs = 0.f;
        #pragma unroll
        for (int nt = 0; nt < 4; ++nt) {
          float e = __expf(sim[nt][r]); sim[nt][r] = e; rs += e;
        }
        rs = sum16(rs);
        float inv = __builtin_amdgcn_rcpf(rs);
        int row = quad * 4 + r;
        #pragma unroll
        for (int nt = 0; nt < 4; ++nt) {
          int col = nt * 16 + l16;
          *(u16*)(P + row * 128 + (((((col >> 3) ^ (row & 7)) << 3) | (col & 7)) << 1)) =
              f2b(sim[nt][r] * inv);
        }
      }
      __builtin_amdgcn_wave_barrier();  // P write -> P read ordering
      bf16x8 pf[2];
      #pragma unroll
      for (int kk = 0; kk < 2; ++kk) {
        int col = kk * 32 + quad * 8;
        pf[kk] = *(const bf16x8*)(P + l16 * 128 + ((((col >> 3) ^ (l16 & 7)) << 4)));
      }
      f32x4 pv[4];
      #pragma unroll
      for (int nt = 0; nt < 4; ++nt) {
        pv[nt] = vzero;
        #pragma unroll
        for (int kk = 0; kk < 2; ++kk) {
          bf16x8 b = *(const bf16x8*)(vt + (nt * 16 + l16) * 64 + kk * 32 + quad * 8);
          pv[nt] = MFMA16(pf[kk], b, pv[nt]);
        }
      }
      #pragma unroll
      for (int nt = 0; nt < 4; ++nt)
        #pragma unroll
        for (int r = 0; r < 4; ++r) {
          float m_ = tier ? aby[r] : abx[r];
          if (tier == 0) o16[h * 4 + nt][r] = m_ * pv[nt][r];
          else           o16[h * 4 + nt][r] += m_ * pv[nt][r];
        }
      __builtin_amdgcn_wave_barrier();  // P read done before next tier/head overwrites
    }
  }

  // ===== out_pre -> Q (reuse), Wo GEMM, store =====
  #pragma unroll
  for (int nt = 0; nt < 16; ++nt) {
    int col = nt * 16 + l16;
    #pragma unroll
    for (int r = 0; r < 4; ++r) {
      int row = quad * 4 + r;
      *(u16*)(Q + row * 512 + (((((col >> 3) ^ (row & 7)) << 3) | (col & 7)) << 1)) =
          f2b(o16[nt][r]);
    }
  }
  __builtin_amdgcn_wave_barrier();
  #pragma unroll
  for (int kk = 0; kk < 8; ++kk) {
    int col = kk * 32 + quad * 8;
    fr[kk] = *(const bf16x8*)(Q + l16 * 512 + ((((col >> 3) ^ (l16 & 7)) << 4)));
  }
  {
    f32x4 o[16];
    #pragma unroll
    for (int nt = 0; nt < 16; ++nt) o[nt] = vzero;
    const u16* WB = ws + OFF_WO + l16 * 256;
    #pragma unroll
    for (int nt = 0; nt < 16; ++nt)
      #pragma unroll
      for (int kk = 0; kk < 8; ++kk) {
        bf16x8 b = *(const bf16x8*)(WB + nt * 4096 + kk * 32 + quad * 8);
        o[nt] = MFMA16(fr[kk], b, o[nt]);
      }
    #pragma unroll
    for (int nt = 0; nt < 16; ++nt) {
      float bv = bo[nt * 16 + l16];
      #pragma unroll
      for (int r = 0; r < 4; ++r) {
        int row = row0 + quad * 4 + r;
        outp[(size_t)row * 256 + nt * 16 + l16] = o[nt][r] + bv;
      }
    }
  }
}

extern "C" void kernel_launch(void* const* d_in, const int* in_sizes, int n_in,
                              void* d_out, int out_size, void* d_ws, size_t ws_size,
                              hipStream_t stream) {
  const float* query   = (const float*)d_in[0];
  const float* context = (const float*)d_in[1];
  const float* fk      = (const float*)d_in[2];
  const float* fv      = (const float*)d_in[3];
  const float* dk      = (const float*)d_in[4];
  const float* dv      = (const float*)d_in[5];
  const float* Wq      = (const float*)d_in[6];
  const float* bq      = (const float*)d_in[7];
  const float* Wg      = (const float*)d_in[8];
  const float* bg      = (const float*)d_in[9];
  const float* Wc1     = (const float*)d_in[10];
  const float* bc1     = (const float*)d_in[11];
  const float* Wc2     = (const float*)d_in[12];
  const float* bc2     = (const float*)d_in[13];
  const float* Wo      = (const float*)d_in[14];
  const float* bo      = (const float*)d_in[15];
  // d_in[16] Ws, d_in[17] bs: dead code (surprise is deleted)
  const float* mixl    = (const float*)d_in[18];
  u16* ws = (u16*)d_ws;
  float* outp = (float*)d_out;

  k_convert<<<256, 256, 0, stream>>>(Wq, Wg, Wc1, Wo, ws);
  k_prep<<<256, 64, 0, stream>>>(fk, fv, dk, dv, ws);
  k_main<<<1024, 256, 0, stream>>>(query, context, bq, bg, bc1, Wc2, bc2, bo,
                                   mixl, ws, outp);
}